// Round 8
// baseline (289.347 us; speedup 1.0000x reference)
//
#include <hip/hip_runtime.h>
#include <hip/hip_bf16.h>

// Problem constants:
//   N_NODES=100000, MAX_DEG=128, NODE_DIM=256, BATCH=4096, NUM_SAMPLES=32
//   group_dim=4, dummy id = 99999
// Output d_out: FLOAT32, concat sel[4096*32], att[4096*32], numnz[4096], dummy[4096];
//               ref values are bf16-rounded -> write bf16-RNE-rounded f32.
//
// R8: transposed phase-2. R7 (121us) was bottlenecked by the per-neighbor
// 64-lane f64 butterfly (12 bpermute + 6 adds per neighbor ~ LDS pipe).
// Now: block = 4 v's, wave w owns v0+w; each lane owns 2 neighbors (lane,
// 64+lane) and accumulates the f64 dot privately over 256 dims with l[v]
// broadcast from LDS. Zero 64-lane reduces; argmin = 2-step 4-lane
// lexicographic (score,pos) min (first-index tie-break). Phase 1 computes
// 4 l-rows per block, amortizing W reads 4x.

constexpr int D        = 256;
constexpr int V        = 4096;
constexpr int MAXDEG   = 128;
constexpr int S        = 32;
constexpr int DUMMY_ID = 99999;

constexpr int OFF_SEL  = 0;
constexpr int OFF_ATT  = V * S;          // 131072
constexpr int OFF_NNZ  = 2 * V * S;      // 262144
constexpr int OFF_DMY  = 2 * V * S + V;  // 266240

__device__ __forceinline__ float bf16_round_f32(float f) {
    unsigned int u = __float_as_uint(f);
    u += 0x7FFFu + ((u >> 16) & 1u);   // RNE to bf16
    u &= 0xFFFF0000u;
    return __uint_as_float(u);
}

__global__ __launch_bounds__(256) void fused_k(
    const int* __restrict__ adj, const float* __restrict__ features,
    const int* __restrict__ ids, const float* __restrict__ W,
    const float* __restrict__ bias, float* __restrict__ out)
{
    const int tid  = threadIdx.x;
    const int lane = tid & 63;
    const int wave = tid >> 6;
    const int v0   = blockIdx.x * 4;

    __shared__ float  vf[4][D];    // features[ids[v0..v0+3]]
    __shared__ double lsh[4][D];   // l rows (f64)

    const int node0 = ids[v0 + 0];
    const int node1 = ids[v0 + 1];
    const int node2 = ids[v0 + 2];
    const int node3 = ids[v0 + 3];

    vf[0][tid] = features[(size_t)node0 * D + tid];
    vf[1][tid] = features[(size_t)node1 * D + tid];
    vf[2][tid] = features[(size_t)node2 * D + tid];
    vf[3][tid] = features[(size_t)node3 * D + tid];

    // att rows are constant 1.0: 4 v's x 32 = 128 consecutive floats
    if (tid < 4 * S) out[OFF_ATT + v0 * S + tid] = 1.0f;
    __syncthreads();

    // Phase 1: l[vi][tid] = b[tid] + sum_d vf[vi][d]*W[d][tid]
    // 4 partial f64 accumulators per vi (r7's passing scheme), W row amortized 4x.
    double a[4][4];
    {
        const double b0 = (double)bias[tid];
        #pragma unroll
        for (int vi = 0; vi < 4; ++vi) {
            a[vi][0] = (vi == vi) ? 0.0 : 0.0;  // init below
            a[vi][1] = 0.0; a[vi][2] = 0.0; a[vi][3] = 0.0;
        }
        a[0][0] = b0; a[1][0] = b0; a[2][0] = b0; a[3][0] = b0;
        #pragma unroll 2
        for (int d = 0; d < D; d += 4) {
            const double w0 = (double)W[(d    ) * D + tid];
            const double w1 = (double)W[(d + 1) * D + tid];
            const double w2 = (double)W[(d + 2) * D + tid];
            const double w3 = (double)W[(d + 3) * D + tid];
            #pragma unroll
            for (int vi = 0; vi < 4; ++vi) {
                a[vi][0] = fma((double)vf[vi][d    ], w0, a[vi][0]);
                a[vi][1] = fma((double)vf[vi][d + 1], w1, a[vi][1]);
                a[vi][2] = fma((double)vf[vi][d + 2], w2, a[vi][2]);
                a[vi][3] = fma((double)vf[vi][d + 3], w3, a[vi][3]);
            }
        }
        #pragma unroll
        for (int vi = 0; vi < 4; ++vi)
            lsh[vi][tid] = (a[vi][0] + a[vi][1]) + (a[vi][2] + a[vi][3]);
    }
    __syncthreads();

    // Phase 2: wave owns v = v0+wave. Lane owns neighbors lane and 64+lane.
    const int v    = v0 + wave;
    const int node = (wave == 0) ? node0 : (wave == 1) ? node1 : (wave == 2) ? node2 : node3;
    const int* arow = adj + (size_t)node * MAXDEG;

    const int nb0 = arow[lane];        // coalesced
    const int nb1 = arow[64 + lane];
    const float* r0 = features + (size_t)nb0 * D;
    const float* r1 = features + (size_t)nb1 * D;
    const double* lrow = lsh[wave];

    double p0a = 0.0, p0b = 0.0, p0c = 0.0, p0d = 0.0;
    double p1a = 0.0, p1b = 0.0, p1c = 0.0, p1d = 0.0;

    #pragma unroll 2
    for (int d = 0; d < D; d += 8) {
        const double2 la = *reinterpret_cast<const double2*>(&lrow[d    ]);  // broadcast
        const double2 lb = *reinterpret_cast<const double2*>(&lrow[d + 2]);
        const double2 lc = *reinterpret_cast<const double2*>(&lrow[d + 4]);
        const double2 ld = *reinterpret_cast<const double2*>(&lrow[d + 6]);
        const float4 x0 = *reinterpret_cast<const float4*>(r0 + d);
        const float4 x1 = *reinterpret_cast<const float4*>(r0 + d + 4);
        const float4 y0 = *reinterpret_cast<const float4*>(r1 + d);
        const float4 y1 = *reinterpret_cast<const float4*>(r1 + d + 4);

        p0a = fma(la.x, (double)x0.x, p0a);
        p0b = fma(la.y, (double)x0.y, p0b);
        p0c = fma(lb.x, (double)x0.z, p0c);
        p0d = fma(lb.y, (double)x0.w, p0d);
        p0a = fma(lc.x, (double)x1.x, p0a);
        p0b = fma(lc.y, (double)x1.y, p0b);
        p0c = fma(ld.x, (double)x1.z, p0c);
        p0d = fma(ld.y, (double)x1.w, p0d);

        p1a = fma(la.x, (double)y0.x, p1a);
        p1b = fma(la.y, (double)y0.y, p1b);
        p1c = fma(lb.x, (double)y0.z, p1c);
        p1d = fma(lb.y, (double)y0.w, p1d);
        p1a = fma(lc.x, (double)y1.x, p1a);
        p1b = fma(lc.y, (double)y1.y, p1b);
        p1c = fma(ld.x, (double)y1.z, p1c);
        p1d = fma(ld.y, (double)y1.w, p1d);
    }

    double s0 = fmax((p0a + p0b) + (p0c + p0d), 0.0);   // relu
    double s1 = fmax((p1a + p1b) + (p1c + p1d), 0.0);

    // Grouped argmin over aligned 4-lane groups, lexicographic (score, pos):
    // strict-first-index semantics identical to np.argmin.
    int pos0 = lane & 3, id0 = nb0;
    int pos1 = lane & 3, id1 = nb1;
    #pragma unroll
    for (int off = 1; off < 4; off <<= 1) {
        const double so0 = __shfl_xor(s0, off);
        const int    po0 = __shfl_xor(pos0, off);
        const int    io0 = __shfl_xor(id0, off);
        if (so0 < s0 || (so0 == s0 && po0 < pos0)) { s0 = so0; pos0 = po0; id0 = io0; }

        const double so1 = __shfl_xor(s1, off);
        const int    po1 = __shfl_xor(pos1, off);
        const int    io1 = __shfl_xor(id1, off);
        if (so1 < s1 || (so1 == s1 && po1 < pos1)) { s1 = so1; pos1 = po1; id1 = io1; }
    }

    const bool winner = (lane & 3) == 0;
    if (winner) {
        const int g = lane >> 2;                       // 0..15
        out[OFF_SEL + v * S + g     ] = bf16_round_f32((float)id0);
        out[OFF_SEL + v * S + 16 + g] = bf16_round_f32((float)id1);
    }

    // non-dummy count via two ballots (winners only contribute)
    const unsigned long long b0 = __ballot(winner && (id0 != DUMMY_ID));
    const unsigned long long b1 = __ballot(winner && (id1 != DUMMY_ID));
    if (lane == 0) {
        const float c = (float)(__popcll(b0) + __popcll(b1));
        out[OFF_NNZ + v] = c;
        out[OFF_DMY + v] = c;
    }
}

extern "C" void kernel_launch(void* const* d_in, const int* in_sizes, int n_in,
                              void* d_out, int out_size, void* d_ws, size_t ws_size,
                              hipStream_t stream)
{
    const int*   adj      = (const int*)d_in[0];
    const float* features = (const float*)d_in[1];
    const int*   ids      = (const int*)d_in[2];
    const float* W        = (const float*)d_in[3];
    const float* bias     = (const float*)d_in[4];
    (void)d_ws; (void)ws_size;  // unused

    float* out = (float*)d_out;

    fused_k<<<V / 4, 256, 0, stream>>>(adj, features, ids, W, bias, out);
}

// Round 9
// 270.913 us; speedup vs baseline: 1.0680x; 1.0680x over previous
//
#include <hip/hip_runtime.h>
#include <hip/hip_bf16.h>

// Problem constants:
//   N_NODES=100000, MAX_DEG=128, NODE_DIM=256, BATCH=4096, NUM_SAMPLES=32
//   group_dim=4, dummy id = 99999
// Output d_out: FLOAT32, concat sel[4096*32], att[4096*32], numnz[4096], dummy[4096];
//               ref values are bf16-rounded -> write bf16-RNE-rounded f32.
//
// R9: transposed phase-2 at FULL occupancy. R8 proved the transpose kills the
// butterfly/bank-conflict cost (conflicts 131072->0) but its 1024-block grid
// gave only 16 waves/CU (occ 35%) -> latency-bound regression. Now: block =
// 2 v's x 2 waves each; lane owns exactly 1 neighbor; grid = 2048 blocks =
// 32 waves/CU requested. launch_bounds(256,8) pins VGPR <= 64 (m69 cliff).

constexpr int D        = 256;
constexpr int V        = 4096;
constexpr int MAXDEG   = 128;
constexpr int S        = 32;
constexpr int DUMMY_ID = 99999;

constexpr int OFF_SEL  = 0;
constexpr int OFF_ATT  = V * S;          // 131072
constexpr int OFF_NNZ  = 2 * V * S;      // 262144
constexpr int OFF_DMY  = 2 * V * S + V;  // 266240

__device__ __forceinline__ float bf16_round_f32(float f) {
    unsigned int u = __float_as_uint(f);
    u += 0x7FFFu + ((u >> 16) & 1u);   // RNE to bf16
    u &= 0xFFFF0000u;
    return __uint_as_float(u);
}

__global__ __launch_bounds__(256, 8) void fused_k(
    const int* __restrict__ adj, const float* __restrict__ features,
    const int* __restrict__ ids, const float* __restrict__ W,
    const float* __restrict__ bias, float* __restrict__ out)
{
    const int tid  = threadIdx.x;
    const int lane = tid & 63;
    const int wave = tid >> 6;
    const int v0   = blockIdx.x * 2;

    __shared__ float  vf[2][D];    // features[ids[v0]], features[ids[v0+1]]
    __shared__ double lsh[2][D];   // l rows (f64)
    __shared__ int    cnt2[2];

    if (tid < 2) cnt2[tid] = 0;

    const int node0 = ids[v0 + 0];
    const int node1 = ids[v0 + 1];
    vf[0][tid] = features[(size_t)node0 * D + tid];
    vf[1][tid] = features[(size_t)node1 * D + tid];

    // att rows are constant 1.0: 2 v's x 32 = 64 consecutive floats
    if (tid < 2 * S) out[OFF_ATT + v0 * S + tid] = 1.0f;
    __syncthreads();

    // Phase 1: l[vi][tid] = b[tid] + sum_d vf[vi][d]*W[d][tid]
    // 4 partial f64 accumulators per vi; W row loads amortized over both v's.
    {
        const double b0 = (double)bias[tid];
        double a00 = b0, a01 = 0.0, a02 = 0.0, a03 = 0.0;
        double a10 = b0, a11 = 0.0, a12 = 0.0, a13 = 0.0;
        #pragma unroll 2
        for (int d = 0; d < D; d += 4) {
            const double w0 = (double)W[(d    ) * D + tid];
            const double w1 = (double)W[(d + 1) * D + tid];
            const double w2 = (double)W[(d + 2) * D + tid];
            const double w3 = (double)W[(d + 3) * D + tid];
            a00 = fma((double)vf[0][d    ], w0, a00);
            a01 = fma((double)vf[0][d + 1], w1, a01);
            a02 = fma((double)vf[0][d + 2], w2, a02);
            a03 = fma((double)vf[0][d + 3], w3, a03);
            a10 = fma((double)vf[1][d    ], w0, a10);
            a11 = fma((double)vf[1][d + 1], w1, a11);
            a12 = fma((double)vf[1][d + 2], w2, a12);
            a13 = fma((double)vf[1][d + 3], w3, a13);
        }
        lsh[0][tid] = (a00 + a01) + (a02 + a03);
        lsh[1][tid] = (a10 + a11) + (a12 + a13);
    }
    __syncthreads();

    // Phase 2: wave = {vh, h}; v = v0+vh; lane owns neighbor h*64+lane.
    const int vh = wave >> 1;          // which v in the block
    const int h  = wave & 1;           // which half of the 128 neighbors
    const int v  = v0 + vh;
    const int node = vh ? node1 : node0;

    const int nb = adj[(size_t)node * MAXDEG + h * 64 + lane];   // coalesced
    const float*  r    = features + (size_t)nb * D;
    const double* lrow = lsh[vh];

    double pa = 0.0, pb = 0.0, pc = 0.0, pd = 0.0;
    #pragma unroll 4
    for (int d = 0; d < D; d += 4) {
        const float4  x  = *reinterpret_cast<const float4*>(r + d);
        const double2 e0 = *reinterpret_cast<const double2*>(&lrow[d]);     // broadcast
        const double2 e1 = *reinterpret_cast<const double2*>(&lrow[d + 2]); // broadcast
        pa = fma(e0.x, (double)x.x, pa);
        pb = fma(e0.y, (double)x.y, pb);
        pc = fma(e1.x, (double)x.z, pc);
        pd = fma(e1.y, (double)x.w, pd);
    }
    double s = fmax((pa + pb) + (pc + pd), 0.0);   // relu

    // Grouped argmin over aligned 4-lane groups, lexicographic (score, pos):
    // identical first-index semantics to np.argmin.
    int pos = lane & 3, id = nb;
    #pragma unroll
    for (int off = 1; off < 4; off <<= 1) {
        const double so = __shfl_xor(s, off);
        const int    po = __shfl_xor(pos, off);
        const int    io = __shfl_xor(id, off);
        if (so < s || (so == s && po < pos)) { s = so; pos = po; id = io; }
    }

    const bool winner = (lane & 3) == 0;
    if (winner)
        out[OFF_SEL + v * S + h * 16 + (lane >> 2)] = bf16_round_f32((float)id);

    // non-dummy count: ballot winners per wave, combine the 2 waves of v in LDS
    const unsigned long long bal = __ballot(winner && (id != DUMMY_ID));
    if (lane == 0) atomicAdd(&cnt2[vh], __popcll(bal));
    __syncthreads();
    if (tid < 2) {
        const float c = (float)cnt2[tid];   // 0..32, exact
        out[OFF_NNZ + v0 + tid] = c;
        out[OFF_DMY + v0 + tid] = c;
    }
}

extern "C" void kernel_launch(void* const* d_in, const int* in_sizes, int n_in,
                              void* d_out, int out_size, void* d_ws, size_t ws_size,
                              hipStream_t stream)
{
    const int*   adj      = (const int*)d_in[0];
    const float* features = (const float*)d_in[1];
    const int*   ids      = (const int*)d_in[2];
    const float* W        = (const float*)d_in[3];
    const float* bias     = (const float*)d_in[4];
    (void)d_ws; (void)ws_size;  // unused

    float* out = (float*)d_out;

    fused_k<<<V / 2, 256, 0, stream>>>(adj, features, ids, W, bias, out);
}